// Round 5
// baseline (111.155 us; speedup 1.0000x reference)
//
#include <hip/hip_runtime.h>

// FutureEncoder: out[b,t,:] = sum_j softmax_j(dot(x[b,t], x[b,t+1+j])) * x[b,t+1+j],
// j in [0,16), valid iff t+1+j < S. fp32 throughout.
//
// Round 5 = DIAGNOSTIC, fixed. R4's failure was __builtin_amdgcn_readfirstlane
// on a float: the builtin is int(int), so the score was VALUE-converted
// (truncated) to int -> absmax 1.1. Reverted to the exec-masked update path
// that passed in R2/R3 (scores are wave-uniform after the 64-lane butterfly,
// so the branch does not actually diverge).
//
// Diagnostic intent unchanged: REPS=4 identical passes (idempotent, output
// bit-identical) make the dispatch ~4x longer so it beats the harness's 40us
// fill kernels into the top-5 profile rows, finally giving us VALUBusy /
// Occupancy / FETCH_SIZE / VGPR_Count for OUR kernel. Opaque per-rep register
// dependency defeats cross-rep CSE.

namespace {
constexpr int kB   = 2;
constexpr int kS   = 4096;
constexpr int kH   = 1024;
constexpr int kK   = 16;
constexpr int kTPW = 2;                 // t's per wave
constexpr int kC   = 2;                 // window rows per chunk
constexpr int kFR  = kH / (64 * 4);     // float4 fragments per lane per row = 4
constexpr int kNV  = kTPW * kC;         // scores per chunk = 4
constexpr int kREPS = 4;                // diagnostic repetition factor
}

template <int REPS>
__global__ __launch_bounds__(256, 4)
void future_encoder_kernel(const float* __restrict__ x, float* __restrict__ out) {
  const int lane = (int)(threadIdx.x & 63);
  const int wave = (int)((blockIdx.x * blockDim.x + threadIdx.x) >> 6);
  const int t0g  = wave * kTPW;
  if (t0g >= kB * kS) return;
  const int b   = t0g / kS;
  const int tl0 = t0g % kS;
  const int col = lane * 4;

  int opaque = 0;  // always 0, but opaque to the compiler after the asm below

  for (int rep = 0; rep < REPS; ++rep) {
    asm volatile("" : "+v"(opaque));   // defeat cross-rep CSE/hoisting
    const float* __restrict__ xb = x   + (size_t)b * kS * kH + opaque;
    float* __restrict__       ob = out + (size_t)b * kS * kH + opaque;

    // Query fragments: lane holds elements {p*256 + lane*4 .. +3}
    float4 xt[kTPW][kFR];
#pragma unroll
    for (int tt = 0; tt < kTPW; ++tt)
#pragma unroll
      for (int p = 0; p < kFR; ++p)
        xt[tt][p] = *(const float4*)(xb + (size_t)(tl0 + tt) * kH + p * 256 + col);

    // Online-softmax state per t
    float m[kTPW], s[kTPW];
    float4 acc[kTPW][kFR];
#pragma unroll
    for (int tt = 0; tt < kTPW; ++tt) {
      m[tt] = -1e30f;
      s[tt] = 0.f;
#pragma unroll
      for (int p = 0; p < kFR; ++p) acc[tt][p] = make_float4(0.f, 0.f, 0.f, 0.f);
    }

    const int rBeg = tl0 + 1;
    const int rEnd = min(tl0 + kTPW - 1 + kK, kS - 1);  // inclusive

    for (int r0 = rBeg; r0 <= rEnd; r0 += kC) {
      // ---- load chunk (independent loads; clamped rows masked at update) ----
      float4 w[kC][kFR];
#pragma unroll
      for (int i = 0; i < kC; ++i) {
        const int r = min(r0 + i, rEnd);
#pragma unroll
        for (int p = 0; p < kFR; ++p)
          w[i][p] = *(const float4*)(xb + (size_t)r * kH + p * 256 + col);
      }

      // ---- partial dots (2 accumulators to shorten the fma chain) ----
      float sc[kNV];
#pragma unroll
      for (int tt = 0; tt < kTPW; ++tt)
#pragma unroll
        for (int i = 0; i < kC; ++i) {
          float a0 = 0.f, a1 = 0.f;
#pragma unroll
          for (int p = 0; p < kFR; ++p) {
            a0 = fmaf(xt[tt][p].x, w[i][p].x, a0);
            a1 = fmaf(xt[tt][p].y, w[i][p].y, a1);
            a0 = fmaf(xt[tt][p].z, w[i][p].z, a0);
            a1 = fmaf(xt[tt][p].w, w[i][p].w, a1);
          }
          sc[tt * kC + i] = a0 + a1;
        }

      // ---- batched butterfly: 4 independent chains pipeline per level ----
#pragma unroll
      for (int off = 32; off >= 1; off >>= 1) {
        float other[kNV];
#pragma unroll
        for (int v = 0; v < kNV; ++v) other[v] = __shfl_xor(sc[v], off, 64);
#pragma unroll
        for (int v = 0; v < kNV; ++v) sc[v] += other[v];
      }

      // ---- online updates (scores wave-uniform -> branch doesn't diverge) ----
#pragma unroll
      for (int tt = 0; tt < kTPW; ++tt)
#pragma unroll
        for (int i = 0; i < kC; ++i) {
          const int r = r0 + i;
          const int d = r - tl0 - tt;
          if (r <= rEnd && d >= 1 && d <= kK) {
            const float v = sc[tt * kC + i];
            if (v <= m[tt]) {
              const float p2 = __expf(v - m[tt]);
              s[tt] += p2;
#pragma unroll
              for (int p = 0; p < kFR; ++p) {
                acc[tt][p].x = fmaf(p2, w[i][p].x, acc[tt][p].x);
                acc[tt][p].y = fmaf(p2, w[i][p].y, acc[tt][p].y);
                acc[tt][p].z = fmaf(p2, w[i][p].z, acc[tt][p].z);
                acc[tt][p].w = fmaf(p2, w[i][p].w, acc[tt][p].w);
              }
            } else {
              const float r2 = __expf(m[tt] - v);   // 0 on first valid row
              m[tt] = v;
              s[tt] = fmaf(s[tt], r2, 1.f);
#pragma unroll
              for (int p = 0; p < kFR; ++p) {
                acc[tt][p].x = fmaf(acc[tt][p].x, r2, w[i][p].x);
                acc[tt][p].y = fmaf(acc[tt][p].y, r2, w[i][p].y);
                acc[tt][p].z = fmaf(acc[tt][p].z, r2, w[i][p].z);
                acc[tt][p].w = fmaf(acc[tt][p].w, r2, w[i][p].w);
              }
            }
          }
        }
    }

    // ---- epilogue: out = acc / s  (s==0 only for t==S-1 -> exact zeros) ----
#pragma unroll
    for (int tt = 0; tt < kTPW; ++tt) {
      const float inv = (s[tt] > 0.f) ? (1.f / s[tt]) : 0.f;
#pragma unroll
      for (int p = 0; p < kFR; ++p) {
        float4 o;
        o.x = acc[tt][p].x * inv;
        o.y = acc[tt][p].y * inv;
        o.z = acc[tt][p].z * inv;
        o.w = acc[tt][p].w * inv;
        *(float4*)(ob + (size_t)(tl0 + tt) * kH + p * 256 + col) = o;
      }
    }
  }
}

extern "C" void kernel_launch(void* const* d_in, const int* in_sizes, int n_in,
                              void* d_out, int out_size, void* d_ws, size_t ws_size,
                              hipStream_t stream) {
  const float* x = (const float*)d_in[0];
  float* out = (float*)d_out;
  constexpr int kWaves   = kB * kS / kTPW;           // 4096 waves
  constexpr int kThreads = 256;
  constexpr int kBlocks  = kWaves * 64 / kThreads;    // 1024 blocks
  hipLaunchKernelGGL(future_encoder_kernel<kREPS>, dim3(kBlocks), dim3(kThreads),
                     0, stream, x, out);
}

// Round 6
// 26.268 us; speedup vs baseline: 4.2315x; 4.2315x over previous
//
#include <hip/hip_runtime.h>

// FutureEncoder: out[b,t,:] = sum_j softmax_j(dot(x[b,t], x[b,t+1+j])) * x[b,t+1+j],
// j in [0,16), valid iff t+1+j < S. fp32 throughout.
//
// Round 6: R5's diagnostic showed latency-bound (VALUBusy 39%, occ 36%, HBM 51%,
// VGPR only 64): the runtime-bounded row loop serialized {load -> vmcnt(0) ->
// compute} per chunk, exposing full L2/L3 latency every 2 rows. Fix: the row
// loop now has a COMPILE-TIME trip count (17 rows, clamped index, uniform
// runtime mask) and is fully unrolled, so the scheduler prefetches loads
// across rows within the VGPR budget. launch_bounds(256,4) -> 128 VGPR cap,
// 4 waves/SIMD (grid cap). XCD strip swizzle kept for L2 locality.

namespace {
constexpr int kB   = 2;
constexpr int kS   = 4096;
constexpr int kH   = 1024;
constexpr int kK   = 16;
constexpr int kTPW = 2;                 // t's per wave
constexpr int kFR  = kH / (64 * 4);     // float4 fragments per lane per row = 4
constexpr int kRows = kK + kTPW - 1;    // 17 distinct window rows per wave
constexpr int kXCD = 8;
constexpr int kWavesPerBlk = 4;
constexpr int kBlocks = kB * kS / (kTPW * kWavesPerBlk);  // 1024
}

__global__ __launch_bounds__(256, 4)
void future_encoder_kernel(const float* __restrict__ x, float* __restrict__ out) {
  const int lane = (int)(threadIdx.x & 63);
  const int wib  = (int)(threadIdx.x >> 6);

  // XCD strip swizzle: HW round-robins blocks over 8 XCDs; give each XCD a
  // contiguous strip of 128 virtual blocks so neighboring t's share its L2.
  const int vb   = (int)(blockIdx.x % kXCD) * (kBlocks / kXCD) + (int)(blockIdx.x / kXCD);
  const int wave = vb * kWavesPerBlk + wib;
  const int t0g  = wave * kTPW;
  const int b    = t0g / kS;
  const int tl0  = t0g % kS;            // 8 | 4096: never crosses batches
  const float* __restrict__ xb = x   + (size_t)b * kS * kH;
  float* __restrict__       ob = out + (size_t)b * kS * kH;
  const int col = lane * 4;

  // Query fragments: lane holds elements {p*256 + lane*4 .. +3}
  float4 xt[kTPW][kFR];
#pragma unroll
  for (int tt = 0; tt < kTPW; ++tt)
#pragma unroll
    for (int p = 0; p < kFR; ++p)
      xt[tt][p] = *(const float4*)(xb + (size_t)(tl0 + tt) * kH + p * 256 + col);

  // Online-softmax state per t
  float m[kTPW], s[kTPW];
  float4 acc[kTPW][kFR];
#pragma unroll
  for (int tt = 0; tt < kTPW; ++tt) {
    m[tt] = -1e30f;
    s[tt] = 0.f;
#pragma unroll
    for (int p = 0; p < kFR; ++p) acc[tt][p] = make_float4(0.f, 0.f, 0.f, 0.f);
  }

  // Fully-unrolled row loop: row j is tl0+1+j, j = 0..16 (compile-time count).
  // Index clamped to S-1 (always-valid memory); updates masked by the
  // wave-uniform runtime test rr < kS. Validity of (t,j) pairs is
  // compile-time after unroll, so dead work is eliminated by the compiler.
#pragma unroll
  for (int j = 0; j < kRows; ++j) {
    const int rr = tl0 + 1 + j;
    const int r  = (rr < kS) ? rr : (kS - 1);

    float4 w[kFR];
#pragma unroll
    for (int p = 0; p < kFR; ++p)
      w[p] = *(const float4*)(xb + (size_t)r * kH + p * 256 + col);

    // Scores for each t with 1 <= (1+j-tt) <= kK  (compile-time per j,tt)
    float sc[kTPW];
#pragma unroll
    for (int tt = 0; tt < kTPW; ++tt) {
      const int d = 1 + j - tt;
      if (d >= 1 && d <= kK) {
        float a0 = 0.f, a1 = 0.f;
#pragma unroll
        for (int p = 0; p < kFR; ++p) {
          a0 = fmaf(xt[tt][p].x, w[p].x, a0);
          a1 = fmaf(xt[tt][p].y, w[p].y, a1);
          a0 = fmaf(xt[tt][p].z, w[p].z, a0);
          a1 = fmaf(xt[tt][p].w, w[p].w, a1);
        }
        sc[tt] = a0 + a1;
      } else {
        sc[tt] = 0.f;
      }
    }

    // Batched butterfly over the (<=2) live chains
#pragma unroll
    for (int off = 32; off >= 1; off >>= 1) {
      float other[kTPW];
#pragma unroll
      for (int tt = 0; tt < kTPW; ++tt) other[tt] = __shfl_xor(sc[tt], off, 64);
#pragma unroll
      for (int tt = 0; tt < kTPW; ++tt) sc[tt] += other[tt];
    }

    // Online updates (scores wave-uniform; runtime mask rr<kS is uniform)
    if (rr < kS) {
#pragma unroll
      for (int tt = 0; tt < kTPW; ++tt) {
        const int d = 1 + j - tt;
        if (d >= 1 && d <= kK) {
          const float v = sc[tt];
          if (v <= m[tt]) {
            const float p2 = __expf(v - m[tt]);
            s[tt] += p2;
#pragma unroll
            for (int p = 0; p < kFR; ++p) {
              acc[tt][p].x = fmaf(p2, w[p].x, acc[tt][p].x);
              acc[tt][p].y = fmaf(p2, w[p].y, acc[tt][p].y);
              acc[tt][p].z = fmaf(p2, w[p].z, acc[tt][p].z);
              acc[tt][p].w = fmaf(p2, w[p].w, acc[tt][p].w);
            }
          } else {
            const float r2 = __expf(m[tt] - v);   // 0 on first valid row
            m[tt] = v;
            s[tt] = fmaf(s[tt], r2, 1.f);
#pragma unroll
            for (int p = 0; p < kFR; ++p) {
              acc[tt][p].x = fmaf(acc[tt][p].x, r2, w[p].x);
              acc[tt][p].y = fmaf(acc[tt][p].y, r2, w[p].y);
              acc[tt][p].z = fmaf(acc[tt][p].z, r2, w[p].z);
              acc[tt][p].w = fmaf(acc[tt][p].w, r2, w[p].w);
            }
          }
        }
      }
    }
  }

  // Epilogue: out = acc / s  (s==0 only for t==S-1 -> exact zeros)
#pragma unroll
  for (int tt = 0; tt < kTPW; ++tt) {
    const float inv = (s[tt] > 0.f) ? (1.f / s[tt]) : 0.f;
#pragma unroll
    for (int p = 0; p < kFR; ++p) {
      float4 o;
      o.x = acc[tt][p].x * inv;
      o.y = acc[tt][p].y * inv;
      o.z = acc[tt][p].z * inv;
      o.w = acc[tt][p].w * inv;
      *(float4*)(ob + (size_t)(tl0 + tt) * kH + p * 256 + col) = o;
    }
  }
}

extern "C" void kernel_launch(void* const* d_in, const int* in_sizes, int n_in,
                              void* d_out, int out_size, void* d_ws, size_t ws_size,
                              hipStream_t stream) {
  const float* x = (const float*)d_in[0];
  float* out = (float*)d_out;
  hipLaunchKernelGGL(future_encoder_kernel, dim3(kBlocks), dim3(256), 0, stream,
                     x, out);
}